// Round 7
// baseline (1834.737 us; speedup 1.0000x reference)
//
#include <hip/hip_runtime.h>
#include <hip/hip_bf16.h>

// ---------------------------------------------------------------------------
// VisionMamba, round 6: direct-fragment GEMMs + MFMA x_proj.
// B=8, L=196, D_MODEL=192, D_INNER=384, D_STATE=16, DT_RANK=12, DEPTH=24.
//
// R6 changes:
//  - cvt_weights: one-pass fp32->bf16 conversion of in_proj/out_proj/pe/xproj
//    weights into workspace (xproj padded 44->48 rows).
//  - gemm_in / gemm_ln: NO LDS, NO k-loop barriers. A/B fragments loaded
//    short8 directly global->VGPR (16 lines/request = coalesced-equivalent;
//    weights L2-resident). K is a template constant -> fully unrolled.
//  - conv_xproj_dt: 14 tokens/block (112 blocks). conv writes bf16 u-tile in
//    MFMA-A layout (LDS); x_proj = 12x3 MFMAs w/ B-frags direct from global
//    bf16; dt_proj float4 weights amortized 14x. Kills the 4-way su bank
//    conflict (was 288/block) and per-token weight re-reads.
// ---------------------------------------------------------------------------

#define NTOK   1568   // B * L
#define DMODEL 192
#define DINNER 384
#define DSTATE 16
#define DTRANK 12
#define DEPTH  24
#define LSEQ   196
#define TCH    49     // scan time-chunk (196 = 4*49)

typedef __attribute__((ext_vector_type(8))) short short8;
typedef __attribute__((ext_vector_type(4))) short short4v;
typedef __attribute__((ext_vector_type(4))) float floatx4;

__device__ inline short f2bf(float f) {
    __hip_bfloat16 h = __float2bfloat16(f);
    return *reinterpret_cast<short*>(&h);
}

// ---------------- weight fp32 -> bf16 conversion (runs every call) ----------------
#define CVT_N1 884736   // in_proj  24*768*192 /4
#define CVT_N2 442368   // out_proj 24*192*384 /4
#define CVT_N3 36864    // pe       192*768    /4
#define CVT_N4 110592   // xproj padded 24*48*384 /4
__global__ __launch_bounds__(256) void cvt_weights(
    const float* __restrict__ inw, const float* __restrict__ outw,
    const float* __restrict__ pew, const float* __restrict__ xpw,
    short* __restrict__ w_in, short* __restrict__ w_out,
    short* __restrict__ w_pe, short* __restrict__ w_xp)
{
    int idx = blockIdx.x * 256 + threadIdx.x;
    float4 v;
    short* dst;
    if (idx < CVT_N1) {
        v = ((const float4*)inw)[idx]; dst = w_in + (size_t)idx * 4;
    } else if (idx < CVT_N1 + CVT_N2) {
        int i = idx - CVT_N1;
        v = ((const float4*)outw)[i]; dst = w_out + (size_t)i * 4;
    } else if (idx < CVT_N1 + CVT_N2 + CVT_N3) {
        int i = idx - CVT_N1 - CVT_N2;
        v = ((const float4*)pew)[i]; dst = w_pe + (size_t)i * 4;
    } else {
        int i = idx - CVT_N1 - CVT_N2 - CVT_N3;
        int layer = i / 4608, rr = i % 4608;
        int row = rr / 96, c4 = (rr % 96) * 4;
        if (row < 44) v = *(const float4*)&xpw[((size_t)layer * 44 + row) * 384 + c4];
        else          v = make_float4(0.f, 0.f, 0.f, 0.f);
        dst = w_xp + ((size_t)layer * 48 + row) * 384 + c4;
    }
    short4v o;
    o[0] = f2bf(v.x); o[1] = f2bf(v.y); o[2] = f2bf(v.z); o[3] = f2bf(v.w);
    *(short4v*)dst = o;
}

// ---------------- im2col for patch embed (bf16 out) ----------------
__global__ __launch_bounds__(256) void im2col(
    const float* __restrict__ x, __hip_bfloat16* __restrict__ patches)
{
    int idx = blockIdx.x * 256 + threadIdx.x;
    if (idx >= NTOK * 768) return;
    int tok = idx / 768, e = idx % 768;
    int b = tok / LSEQ, l = tok % LSEQ;
    int py = l / 14, px = l % 14;
    int ic = e >> 8, rem = e & 255, ky = rem >> 4, kx = rem & 15;
    patches[idx] = __float2bfloat16(x[((b * 3 + ic) * 224 + py * 16 + ky) * 224 + px * 16 + kx]);
}

// ---------------- gemm_in: xz[M,768] = hn[M,192] @ W[768,192]^T (all frags direct) ----------------
template<int K>
__global__ __launch_bounds__(256) void gemm_in(
    const __hip_bfloat16* __restrict__ A, const short* __restrict__ Wb,
    float* __restrict__ C, int M, int N)
{
    int tid = threadIdx.x;
    int m0 = blockIdx.x * 64, n0 = blockIdx.y * 64;
    int wv = tid >> 6, lane = tid & 63;
    int fm = lane & 15, q = lane >> 4;
    int m = m0 + wv * 16 + fm;
    const short* Ab = (const short*)A;
    floatx4 acc[4];
#pragma unroll
    for (int nt = 0; nt < 4; ++nt) acc[nt] = (floatx4){0.f, 0.f, 0.f, 0.f};
#pragma unroll
    for (int k0 = 0; k0 < K; k0 += 32) {
        short8 af = {0,0,0,0,0,0,0,0};
        if (m < M) af = *(const short8*)&Ab[(size_t)m * K + k0 + q * 8];
#pragma unroll
        for (int nt = 0; nt < 4; ++nt) {
            short8 bf = *(const short8*)&Wb[(size_t)(n0 + nt * 16 + fm) * K + k0 + q * 8];
            acc[nt] = __builtin_amdgcn_mfma_f32_16x16x32_bf16(af, bf, acc[nt], 0, 0, 0);
        }
    }
#pragma unroll
    for (int nt = 0; nt < 4; ++nt) {
        int col = n0 + nt * 16 + fm;
#pragma unroll
        for (int r = 0; r < 4; ++r) {
            int mrow = m0 + wv * 16 + q * 4 + r;
            if (mrow < M) C[(size_t)mrow * N + col] = acc[nt][r];
        }
    }
}

// ---------------- gemm_ln: 16-row tiles, direct frags, fused residual+LN ----------------
template<int K>
__global__ __launch_bounds__(256) void gemm_ln(
    const __hip_bfloat16* __restrict__ A, const short* __restrict__ Wb,
    const float* __restrict__ bias, float* __restrict__ residual,
    __hip_bfloat16* __restrict__ hn, float* __restrict__ outf,
    const float* __restrict__ lnw, const float* __restrict__ lnb,
    int accumulate)
{
    __shared__ float slw[192], slb[192], sbias[192];
    __shared__ float sS1[4][16], sS2[4][16];
    int tid = threadIdx.x;
    int m0 = blockIdx.x * 16;
    int wv = tid >> 6, lane = tid & 63;
    int fm = lane & 15, q = lane >> 4;
    if (tid < 192) {
        slw[tid] = lnw[tid];
        slb[tid] = lnb[tid];
        sbias[tid] = bias ? bias[tid] : 0.f;
    }
    const short* Ab = (const short*)A;
    floatx4 acc[3];
#pragma unroll
    for (int j = 0; j < 3; ++j) acc[j] = (floatx4){0.f, 0.f, 0.f, 0.f};
#pragma unroll
    for (int k0 = 0; k0 < K; k0 += 32) {
        short8 af = *(const short8*)&Ab[(size_t)(m0 + fm) * K + k0 + q * 8];
#pragma unroll
        for (int j = 0; j < 3; ++j) {
            int n = (wv * 3 + j) * 16 + fm;
            short8 bf = *(const short8*)&Wb[(size_t)n * K + k0 + q * 8];
            acc[j] = __builtin_amdgcn_mfma_f32_16x16x32_bf16(af, bf, acc[j], 0, 0, 0);
        }
    }
    __syncthreads();   // sbias/slw/slb ready

    float v[3][4];
#pragma unroll
    for (int r = 0; r < 4; ++r) {
        int m = m0 + q * 4 + r;
#pragma unroll
        for (int j = 0; j < 3; ++j) {
            int col = (wv * 3 + j) * 16 + fm;
            float t = acc[j][r] + sbias[col];
            if (accumulate) t += residual[(size_t)m * DMODEL + col];
            v[j][r] = t;
        }
    }
#pragma unroll
    for (int r = 0; r < 4; ++r) {
        int m = m0 + q * 4 + r;
#pragma unroll
        for (int j = 0; j < 3; ++j)
            residual[(size_t)m * DMODEL + (wv * 3 + j) * 16 + fm] = v[j][r];
    }
#pragma unroll
    for (int r = 0; r < 4; ++r) {
        float s1 = v[0][r] + v[1][r] + v[2][r];
        float s2 = v[0][r]*v[0][r] + v[1][r]*v[1][r] + v[2][r]*v[2][r];
        s1 += __shfl_xor(s1, 1); s2 += __shfl_xor(s2, 1);
        s1 += __shfl_xor(s1, 2); s2 += __shfl_xor(s2, 2);
        s1 += __shfl_xor(s1, 4); s2 += __shfl_xor(s2, 4);
        s1 += __shfl_xor(s1, 8); s2 += __shfl_xor(s2, 8);
        if (fm == 0) { sS1[wv][q * 4 + r] = s1; sS2[wv][q * 4 + r] = s2; }
    }
    __syncthreads();
#pragma unroll
    for (int r = 0; r < 4; ++r) {
        int row = q * 4 + r;
        int m = m0 + row;
        float S1 = sS1[0][row] + sS1[1][row] + sS1[2][row] + sS1[3][row];
        float S2 = sS2[0][row] + sS2[1][row] + sS2[2][row] + sS2[3][row];
        float mean = S1 * (1.f / DMODEL);
        float var  = S2 * (1.f / DMODEL) - mean * mean;
        float rstd = rsqrtf(var + 1e-5f);
#pragma unroll
        for (int j = 0; j < 3; ++j) {
            int col = (wv * 3 + j) * 16 + fm;
            float o = (v[j][r] - mean) * rstd * slw[col] + slb[col];
            if (outf) outf[(size_t)m * DMODEL + col] = o;
            else      hn[(size_t)m * DMODEL + col] = __float2bfloat16(o);
        }
    }
}

// ---------------- conv + silu + MFMA x_proj + dt(softplus) ----------------
// grid = 8 * 14 = 112 blocks, 14 tokens each. su16: bf16 u-tile in MFMA-A
// layout [16 rows=tok][384 k], stride 392. x_proj B-frags direct from global
// bf16 (44->48 padded rows). sx[14][48] holds xdbl in fp32.
__global__ __launch_bounds__(256) void conv_xproj_dt(
    const float* __restrict__ xz, const float* __restrict__ cw,
    const float* __restrict__ cb, const short* __restrict__ xpb,
    const float* __restrict__ dtw, const float* __restrict__ dtb,
    float* __restrict__ u, float* __restrict__ dtg, float* __restrict__ bcg)
{
    __shared__ short su16[16 * 392];
    __shared__ float sx[14 * 48];
    int bx = blockIdx.x;
    int b = bx / 14, c = bx % 14;
    int l0 = c * 14;
    int tid = threadIdx.x;

    // conv + SiLU for 14 tokens x 384 channels
    for (int idx = tid; idx < 14 * 384; idx += 256) {
        int t = idx / 384, d = idx % 384;
        int l = l0 + t;
        size_t tok = (size_t)(b * LSEQ + l);
        float4 w4 = *(const float4*)&cw[d * 4];
        float acc = cb[d];
        int li = l - 3;
        if (li >= 0)     acc += xz[(size_t)(b * LSEQ + li    ) * 768 + d] * w4.x;
        if (li + 1 >= 0) acc += xz[(size_t)(b * LSEQ + li + 1) * 768 + d] * w4.y;
        if (li + 2 >= 0) acc += xz[(size_t)(b * LSEQ + li + 2) * 768 + d] * w4.z;
        acc += xz[tok * 768 + d] * w4.w;
        float sig = 1.f / (1.f + __expf(-acc));
        float val = acc * sig;
        u[tok * 384 + d] = val;
        su16[t * 392 + d] = f2bf(val);
    }
    for (int idx = tid; idx < 2 * 384; idx += 256) {   // zero pad rows 14,15
        int t = 14 + idx / 384, d = idx % 384;
        su16[t * 392 + d] = 0;
    }
    __syncthreads();

    // x_proj: 3 n-tiles (48 cols, 44 valid), 12 k-steps; wave wv owns tile wv
    int wv = tid >> 6, lane = tid & 63;
    int fm = lane & 15, q = lane >> 4;
    if (wv < 3) {
        floatx4 acc = {0.f, 0.f, 0.f, 0.f};
#pragma unroll
        for (int ks = 0; ks < 12; ++ks) {
            short8 af = *(const short8*)&su16[fm * 392 + ks * 32 + q * 8];
            short8 bf = *(const short8*)&xpb[(size_t)(wv * 16 + fm) * 384 + ks * 32 + q * 8];
            acc = __builtin_amdgcn_mfma_f32_16x16x32_bf16(af, bf, acc, 0, 0, 0);
        }
#pragma unroll
        for (int r = 0; r < 4; ++r) {
            int t = q * 4 + r;
            if (t < 14) sx[t * 48 + wv * 16 + fm] = acc[r];
        }
    }
    __syncthreads();

    // dt = softplus(sx[:, :12] @ dtw^T + dtb); weights amortized over 14 tokens
    for (int d = tid; d < 384; d += 256) {
        float4 wa = *(const float4*)&dtw[d * 12];
        float4 wb = *(const float4*)&dtw[d * 12 + 4];
        float4 wc = *(const float4*)&dtw[d * 12 + 8];
        float bias = dtb[d];
#pragma unroll
        for (int t = 0; t < 14; ++t) {
            const float* sxr = &sx[t * 48];
            float a = bias;
            a += sxr[0]*wa.x + sxr[1]*wa.y + sxr[2] *wa.z + sxr[3] *wa.w;
            a += sxr[4]*wb.x + sxr[5]*wb.y + sxr[6] *wb.z + sxr[7] *wb.w;
            a += sxr[8]*wc.x + sxr[9]*wc.y + sxr[10]*wc.z + sxr[11]*wc.w;
            float sp = (a > 20.f) ? a : log1pf(__expf(a));
            dtg[(size_t)(b * LSEQ + l0 + t) * 384 + d] = sp;
        }
    }
    // B (16) and C (16) per token
    if (tid < 448) {
        int t = tid >> 5, j = tid & 31;
        bcg[(size_t)(b * LSEQ + l0 + t) * 32 + j] = sx[t * 48 + 12 + j];
    }
}

// ---------------- selective scan + gating (3-phase, latency-free) ----------------
#define SPAD 272
__global__ __launch_bounds__(256) void scan_kernel(
    const float* __restrict__ u, const float* __restrict__ dtg,
    const float* __restrict__ bc, const float* __restrict__ xz,
    const float* __restrict__ Alog, const float* __restrict__ Dp,
    __hip_bfloat16* __restrict__ y)
{
    __shared__ float sdt[TCH][16];
    __shared__ float su_[TCH][16];
    __shared__ float sz_[TCH][16];
    __shared__ float sB_[TCH][16];
    __shared__ float sC_[TCH][16];
    __shared__ float sprod[TCH][SPAD];

    int b  = blockIdx.x / 24;
    int dg = blockIdx.x % 24;
    int tid = threadIdx.x;
    int s = tid & 15, dl = tid >> 4;
    int d = dg * 16 + dl;
    float Ads = -expf(Alog[d * DSTATE + s]);
    float Dd2 = Dp[dg * 16 + (tid & 15)];
    float h = 0.f;

    for (int c0 = 0; c0 < LSEQ; c0 += TCH) {
        if (tid < TCH * 4) {
            int t = tid >> 2, j4 = (tid & 3) * 4;
            size_t tok = (size_t)(b * LSEQ + c0 + t);
            *(float4*)&sdt[t][j4] = *(const float4*)&dtg[tok * DINNER + dg * 16 + j4];
            *(float4*)&su_[t][j4] = *(const float4*)&u  [tok * DINNER + dg * 16 + j4];
            *(float4*)&sz_[t][j4] = *(const float4*)&xz [tok * 768 + DINNER + dg * 16 + j4];
            *(float4*)&sB_[t][j4] = *(const float4*)&bc [tok * 32 + j4];
            *(float4*)&sC_[t][j4] = *(const float4*)&bc [tok * 32 + 16 + j4];
        }
        __syncthreads();

#pragma unroll 7
        for (int t = 0; t < TCH; ++t) {
            float dtv = sdt[t][dl];
            float uv  = su_[t][dl];
            float Bv  = sB_[t][s];
            float Cv  = sC_[t][s];
            float dA  = __expf(dtv * Ads);
            h = dA * h + (dtv * uv) * Bv;
            sprod[t][dl * 17 + s] = h * Cv;
        }
        __syncthreads();

        for (int i = tid; i < TCH * 16; i += 256) {
            int t = i >> 4, dl2 = i & 15;
            float sum = 0.f;
#pragma unroll
            for (int j = 0; j < 16; ++j) sum += sprod[t][dl2 * 17 + j];
            float uv = su_[t][dl2];
            float zv = sz_[t][dl2];
            float sig = 1.f / (1.f + __expf(-zv));
            y[(size_t)(b * LSEQ + c0 + t) * DINNER + dg * 16 + dl2] =
                __float2bfloat16((sum + uv * Dd2) * (zv * sig));
        }
        __syncthreads();
    }
}

// ---------------------------------------------------------------------------
extern "C" void kernel_launch(void* const* d_in, const int* in_sizes, int n_in,
                              void* d_out, int out_size, void* d_ws, size_t ws_size,
                              hipStream_t stream)
{
    const float* x         = (const float*)d_in[0];
    const float* pe_w      = (const float*)d_in[1];
    const float* pe_b      = (const float*)d_in[2];
    const float* norm_w    = (const float*)d_in[3];
    const float* norm_b    = (const float*)d_in[4];
    const float* in_proj_w = (const float*)d_in[5];
    const float* conv_w    = (const float*)d_in[6];
    const float* conv_b    = (const float*)d_in[7];
    const float* xproj_w   = (const float*)d_in[8];
    const float* dtproj_w  = (const float*)d_in[9];
    const float* dtproj_b  = (const float*)d_in[10];
    const float* A_log     = (const float*)d_in[11];
    const float* D_param   = (const float*)d_in[12];
    const float* outproj_w = (const float*)d_in[13];
    const float* normf_w   = (const float*)d_in[14];
    const float* normf_b   = (const float*)d_in[15];

    float* ws = (float*)d_ws;
    float* residual = ws;                       // 301056 f32
    float* xz       = residual + 301056;        // 1204224 f32
    float* ubuf     = xz + 1204224;             // 602112 f32
    float* dtbuf    = ubuf + 602112;            // 602112 f32
    float* bcbuf    = dtbuf + 602112;           // 50176 f32
    __hip_bfloat16* hn      = (__hip_bfloat16*)(ws + 2759680);  // 301056 bf16
    __hip_bfloat16* ybf     = (__hip_bfloat16*)(ws + 2910208);  // 602112 bf16
    __hip_bfloat16* patches = (__hip_bfloat16*)(ws + 3211264);  // 1204224 bf16
    short* w_in  = (short*)(ws + 3813376);      // 3538944 bf16
    short* w_out = (short*)(ws + 5582848);      // 1769472 bf16
    short* w_pe  = (short*)(ws + 6467584);      // 147456 bf16
    short* w_xp  = (short*)(ws + 6541312);      // 442368 bf16 (48-row padded)

    cvt_weights<<<5760, 256, 0, stream>>>(
        in_proj_w, outproj_w, pe_w, xproj_w, w_in, w_out, w_pe, w_xp);

    im2col<<<(NTOK * 768 + 255) / 256, 256, 0, stream>>>(x, patches);
    gemm_ln<768><<<98, 256, 0, stream>>>(
        patches, w_pe, pe_b, residual, hn, nullptr, norm_w, norm_b, 0);

    for (int i = 0; i < DEPTH; ++i) {
        int last = (i == DEPTH - 1);
        gemm_in<192><<<dim3(25, 12), 256, 0, stream>>>(
            hn, w_in + (size_t)i * 768 * DMODEL, xz, NTOK, 768);
        conv_xproj_dt<<<112, 256, 0, stream>>>(
            xz, conv_w + (size_t)i * DINNER * 4, conv_b + (size_t)i * DINNER,
            w_xp + (size_t)i * 48 * DINNER, dtproj_w + (size_t)i * DINNER * DTRANK,
            dtproj_b + (size_t)i * DINNER, ubuf, dtbuf, bcbuf);
        scan_kernel<<<192, 256, 0, stream>>>(
            ubuf, dtbuf, bcbuf, xz, A_log + (size_t)i * DINNER * DSTATE,
            D_param + (size_t)i * DINNER, ybf);
        gemm_ln<384><<<98, 256, 0, stream>>>(
            ybf, w_out + (size_t)i * DMODEL * DINNER, nullptr, residual, hn,
            last ? (float*)d_out : nullptr,
            last ? normf_w : norm_w + (i + 1) * DMODEL,
            last ? normf_b : norm_b + (i + 1) * DMODEL,
            1);
    }
}

// Round 8
// 1465.425 us; speedup vs baseline: 1.2520x; 1.2520x over previous
//
#include <hip/hip_runtime.h>
#include <hip/hip_bf16.h>

// ---------------------------------------------------------------------------
// VisionMamba, round 7: revert to R5 LDS-staged GEMMs + keep bf16 weights.
// B=8, L=196, D_MODEL=192, D_INNER=384, D_STATE=16, DT_RANK=12, DEPTH=24.
//
// R7 (fixes R6 regression): R6's direct-fragment loads were TA-bound (16
// 64B-line splits per fragment load). Back to R5's LDS-staged k-loops, but
// W-staging is now a raw short8 copy from pre-converted bf16 weights
// (cvt_weights kept from R6). conv_xproj_dt back to 1568 blocks with su
// stored [4][97] to kill the measured 4-way bank conflict (451K/dispatch).
// ---------------------------------------------------------------------------

#define NTOK   1568   // B * L
#define DMODEL 192
#define DINNER 384
#define DSTATE 16
#define DTRANK 12
#define DEPTH  24
#define LSEQ   196
#define TCH    49     // scan time-chunk (196 = 4*49)

typedef __attribute__((ext_vector_type(8))) short short8;
typedef __attribute__((ext_vector_type(4))) short short4v;
typedef __attribute__((ext_vector_type(4))) float floatx4;

__device__ inline short f2bf(float f) {
    __hip_bfloat16 h = __float2bfloat16(f);
    return *reinterpret_cast<short*>(&h);
}

// ---------------- weight fp32 -> bf16 conversion (in/out/pe) ----------------
#define CVT_N1 884736   // in_proj  24*768*192 /4
#define CVT_N2 442368   // out_proj 24*192*384 /4
#define CVT_N3 36864    // pe       192*768    /4
__global__ __launch_bounds__(256) void cvt_weights(
    const float* __restrict__ inw, const float* __restrict__ outw,
    const float* __restrict__ pew,
    short* __restrict__ w_in, short* __restrict__ w_out,
    short* __restrict__ w_pe)
{
    int idx = blockIdx.x * 256 + threadIdx.x;
    float4 v;
    short* dst;
    if (idx < CVT_N1) {
        v = ((const float4*)inw)[idx]; dst = w_in + (size_t)idx * 4;
    } else if (idx < CVT_N1 + CVT_N2) {
        int i = idx - CVT_N1;
        v = ((const float4*)outw)[i]; dst = w_out + (size_t)i * 4;
    } else if (idx < CVT_N1 + CVT_N2 + CVT_N3) {
        int i = idx - CVT_N1 - CVT_N2;
        v = ((const float4*)pew)[i]; dst = w_pe + (size_t)i * 4;
    } else {
        return;
    }
    short4v o;
    o[0] = f2bf(v.x); o[1] = f2bf(v.y); o[2] = f2bf(v.z); o[3] = f2bf(v.w);
    *(short4v*)dst = o;
}

// ---------------- im2col for patch embed (bf16 out) ----------------
__global__ __launch_bounds__(256) void im2col(
    const float* __restrict__ x, __hip_bfloat16* __restrict__ patches)
{
    int idx = blockIdx.x * 256 + threadIdx.x;
    if (idx >= NTOK * 768) return;
    int tok = idx / 768, e = idx % 768;
    int b = tok / LSEQ, l = tok % LSEQ;
    int py = l / 14, px = l % 14;
    int ic = e >> 8, rem = e & 255, ky = rem >> 4, kx = rem & 15;
    patches[idx] = __float2bfloat16(x[((b * 3 + ic) * 224 + py * 16 + ky) * 224 + px * 16 + kx]);
}

#define LDA 40   // LDS row stride in bf16 elements (80B): uniform bank spread

// ---------------- gemm_in: xz[M,768] = hn[M,192] @ W[768,192]^T ----------------
// 64x64 tile, LDS-staged; A is bf16, W pre-converted bf16 (raw short8 copy).
template<int K>
__global__ __launch_bounds__(256) void gemm_in(
    const __hip_bfloat16* __restrict__ A, const short* __restrict__ Wb,
    float* __restrict__ C, int M, int N)
{
    __shared__ short As[64 * LDA];
    __shared__ short Ws[64 * LDA];
    int tid = threadIdx.x;
    int m0 = blockIdx.x * 64, n0 = blockIdx.y * 64;
    int wv = tid >> 6, lane = tid & 63;
    int fm = lane & 15, q = lane >> 4;
    int row = tid >> 2, kc = (tid & 3) * 8;
    const short* Ab = (const short*)A;
    floatx4 acc[4];
#pragma unroll
    for (int nt = 0; nt < 4; ++nt) acc[nt] = (floatx4){0.f, 0.f, 0.f, 0.f};

#pragma unroll
    for (int k0 = 0; k0 < K; k0 += 32) {
        {
            int m = m0 + row;
            short8 v = {0,0,0,0,0,0,0,0};
            if (m < M) v = *(const short8*)&Ab[(size_t)m * K + k0 + kc];
            *(short8*)&As[row * LDA + kc] = v;
        }
        {
            short8 w = *(const short8*)&Wb[(size_t)(n0 + row) * K + k0 + kc];
            *(short8*)&Ws[row * LDA + kc] = w;
        }
        __syncthreads();
        short8 af = *(const short8*)&As[(wv * 16 + fm) * LDA + q * 8];
#pragma unroll
        for (int nt = 0; nt < 4; ++nt) {
            short8 bf = *(const short8*)&Ws[(nt * 16 + fm) * LDA + q * 8];
            acc[nt] = __builtin_amdgcn_mfma_f32_16x16x32_bf16(af, bf, acc[nt], 0, 0, 0);
        }
        __syncthreads();
    }
#pragma unroll
    for (int nt = 0; nt < 4; ++nt) {
        int col = n0 + nt * 16 + fm;
#pragma unroll
        for (int r = 0; r < 4; ++r) {
            int mrow = m0 + wv * 16 + q * 4 + r;
            if (mrow < M) C[(size_t)mrow * N + col] = acc[nt][r];
        }
    }
}

// ---------------- gemm_ln: 16-row tiles, pipelined LDS, fused residual+LN ----------------
// grid = 98 (NTOK/16). Wave w owns col-tiles 3w..3w+2. Prefetch k+1 into regs.
template<int K>
__global__ __launch_bounds__(256) void gemm_ln(
    const __hip_bfloat16* __restrict__ A, const short* __restrict__ Wb,
    const float* __restrict__ bias, float* __restrict__ residual,
    __hip_bfloat16* __restrict__ hn, float* __restrict__ outf,
    const float* __restrict__ lnw, const float* __restrict__ lnb,
    int accumulate)
{
    __shared__ short As[16 * LDA];
    __shared__ short Ws[192 * LDA];
    __shared__ float slw[192], slb[192], sbias[192];
    __shared__ float sS1[4][16], sS2[4][16];
    int tid = threadIdx.x;
    int m0 = blockIdx.x * 16;
    int wv = tid >> 6, lane = tid & 63;
    int fm = lane & 15, q = lane >> 4;
    int wrow = tid >> 2, kc = (tid & 3) * 8;
    if (tid < 192) {
        slw[tid] = lnw[tid];
        slb[tid] = lnb[tid];
        sbias[tid] = bias ? bias[tid] : 0.f;
    }
    const short* Ab = (const short*)A;
    floatx4 acc[3];
#pragma unroll
    for (int j = 0; j < 3; ++j) acc[j] = (floatx4){0.f, 0.f, 0.f, 0.f};

    // prologue: load k0=0 into regs
    short8 aR = {0,0,0,0,0,0,0,0};
    short8 wR[3];
    if (tid < 64) aR = *(const short8*)&Ab[(size_t)(m0 + (tid >> 2)) * K + kc];
#pragma unroll
    for (int j = 0; j < 3; ++j)
        wR[j] = *(const short8*)&Wb[(size_t)(wrow + 64 * j) * K + kc];

    for (int k0 = 0; k0 < K; k0 += 32) {
        if (tid < 64) *(short8*)&As[(tid >> 2) * LDA + kc] = aR;
#pragma unroll
        for (int j = 0; j < 3; ++j)
            *(short8*)&Ws[(wrow + 64 * j) * LDA + kc] = wR[j];
        __syncthreads();
        int kn = k0 + 32;
        if (kn < K) {
            if (tid < 64) aR = *(const short8*)&Ab[(size_t)(m0 + (tid >> 2)) * K + kn + kc];
#pragma unroll
            for (int j = 0; j < 3; ++j)
                wR[j] = *(const short8*)&Wb[(size_t)(wrow + 64 * j) * K + kn + kc];
        }
        short8 af = *(const short8*)&As[fm * LDA + q * 8];
#pragma unroll
        for (int j = 0; j < 3; ++j) {
            int ct = wv * 3 + j;
            short8 bf = *(const short8*)&Ws[(ct * 16 + fm) * LDA + q * 8];
            acc[j] = __builtin_amdgcn_mfma_f32_16x16x32_bf16(af, bf, acc[j], 0, 0, 0);
        }
        __syncthreads();
    }

    // ---- fused epilogue: residual += C(+bias); LN(residual) -> hn/outf ----
    float v[3][4];
#pragma unroll
    for (int r = 0; r < 4; ++r) {
        int m = m0 + q * 4 + r;
#pragma unroll
        for (int j = 0; j < 3; ++j) {
            int col = (wv * 3 + j) * 16 + fm;
            float t = acc[j][r] + sbias[col];
            if (accumulate) t += residual[(size_t)m * DMODEL + col];
            v[j][r] = t;
        }
    }
#pragma unroll
    for (int r = 0; r < 4; ++r) {
        int m = m0 + q * 4 + r;
#pragma unroll
        for (int j = 0; j < 3; ++j)
            residual[(size_t)m * DMODEL + (wv * 3 + j) * 16 + fm] = v[j][r];
    }
#pragma unroll
    for (int r = 0; r < 4; ++r) {
        float s1 = v[0][r] + v[1][r] + v[2][r];
        float s2 = v[0][r]*v[0][r] + v[1][r]*v[1][r] + v[2][r]*v[2][r];
        s1 += __shfl_xor(s1, 1); s2 += __shfl_xor(s2, 1);
        s1 += __shfl_xor(s1, 2); s2 += __shfl_xor(s2, 2);
        s1 += __shfl_xor(s1, 4); s2 += __shfl_xor(s2, 4);
        s1 += __shfl_xor(s1, 8); s2 += __shfl_xor(s2, 8);
        if (fm == 0) { sS1[wv][q * 4 + r] = s1; sS2[wv][q * 4 + r] = s2; }
    }
    __syncthreads();
#pragma unroll
    for (int r = 0; r < 4; ++r) {
        int row = q * 4 + r;
        int m = m0 + row;
        float S1 = sS1[0][row] + sS1[1][row] + sS1[2][row] + sS1[3][row];
        float S2 = sS2[0][row] + sS2[1][row] + sS2[2][row] + sS2[3][row];
        float mean = S1 * (1.f / DMODEL);
        float var  = S2 * (1.f / DMODEL) - mean * mean;
        float rstd = rsqrtf(var + 1e-5f);
#pragma unroll
        for (int j = 0; j < 3; ++j) {
            int col = (wv * 3 + j) * 16 + fm;
            float o = (v[j][r] - mean) * rstd * slw[col] + slb[col];
            if (outf) outf[(size_t)m * DMODEL + col] = o;
            else      hn[(size_t)m * DMODEL + col] = __float2bfloat16(o);
        }
    }
}

// ---------------- conv + silu + x_proj + dt(softplus) ----------------
// R5 structure (1568 blocks) + su stored [4][97] to break the 4-way bank
// conflict in the x_proj reads (su[p*96+j] had all 4 p on one bank).
__global__ __launch_bounds__(256) void conv_xproj_dt(
    const float* __restrict__ xz, const float* __restrict__ cw,
    const float* __restrict__ cb, const float* __restrict__ xpw,
    const float* __restrict__ dtw, const float* __restrict__ dtb,
    float* __restrict__ u, float* __restrict__ dtg, float* __restrict__ bcg)
{
    __shared__ float su[4][97];
    __shared__ float sx[44];
    int blk = blockIdx.x;
    int b = blk / LSEQ, l = blk % LSEQ;
    int tid = threadIdx.x;
    for (int d = tid; d < DINNER; d += 256) {
        float acc = cb[d];
        float4 w4 = *(const float4*)&cw[d * 4];
        int li = l - 3;
        if (li >= 0)     acc += xz[(size_t)(b * LSEQ + li    ) * 768 + d] * w4.x;
        if (li + 1 >= 0) acc += xz[(size_t)(b * LSEQ + li + 1) * 768 + d] * w4.y;
        if (li + 2 >= 0) acc += xz[(size_t)(b * LSEQ + li + 2) * 768 + d] * w4.z;
        acc += xz[(size_t)(b * LSEQ + l) * 768 + d] * w4.w;
        float sig = 1.f / (1.f + __expf(-acc));
        float val = acc * sig;
        su[d / 96][d % 96] = val;
        u[(size_t)(b * LSEQ + l) * DINNER + d] = val;
    }
    __syncthreads();
    if (tid < 176) {
        int e = tid >> 2, p = tid & 3;
        float acc = 0.f;
        const float* wr = &xpw[e * DINNER + p * 96];
        const float* ur = &su[p][0];
#pragma unroll 8
        for (int j = 0; j < 96; ++j) acc += ur[j] * wr[j];
        acc += __shfl_xor(acc, 1);
        acc += __shfl_xor(acc, 2);
        if (p == 0) sx[e] = acc;
    }
    __syncthreads();
    for (int d = tid; d < DINNER; d += 256) {
        float acc = dtb[d];
#pragma unroll
        for (int r = 0; r < DTRANK; ++r) acc += sx[r] * dtw[d * DTRANK + r];
        float sp = (acc > 20.f) ? acc : log1pf(__expf(acc));
        dtg[(size_t)(b * LSEQ + l) * DINNER + d] = sp;
    }
    if (tid < 32) bcg[(b * LSEQ + l) * 32 + tid] = sx[DTRANK + tid];
}

// ---------------- selective scan + gating (3-phase, latency-free) ----------------
#define SPAD 272
__global__ __launch_bounds__(256) void scan_kernel(
    const float* __restrict__ u, const float* __restrict__ dtg,
    const float* __restrict__ bc, const float* __restrict__ xz,
    const float* __restrict__ Alog, const float* __restrict__ Dp,
    __hip_bfloat16* __restrict__ y)
{
    __shared__ float sdt[TCH][16];
    __shared__ float su_[TCH][16];
    __shared__ float sz_[TCH][16];
    __shared__ float sB_[TCH][16];
    __shared__ float sC_[TCH][16];
    __shared__ float sprod[TCH][SPAD];

    int b  = blockIdx.x / 24;
    int dg = blockIdx.x % 24;
    int tid = threadIdx.x;
    int s = tid & 15, dl = tid >> 4;
    int d = dg * 16 + dl;
    float Ads = -expf(Alog[d * DSTATE + s]);
    float Dd2 = Dp[dg * 16 + (tid & 15)];
    float h = 0.f;

    for (int c0 = 0; c0 < LSEQ; c0 += TCH) {
        if (tid < TCH * 4) {
            int t = tid >> 2, j4 = (tid & 3) * 4;
            size_t tok = (size_t)(b * LSEQ + c0 + t);
            *(float4*)&sdt[t][j4] = *(const float4*)&dtg[tok * DINNER + dg * 16 + j4];
            *(float4*)&su_[t][j4] = *(const float4*)&u  [tok * DINNER + dg * 16 + j4];
            *(float4*)&sz_[t][j4] = *(const float4*)&xz [tok * 768 + DINNER + dg * 16 + j4];
            *(float4*)&sB_[t][j4] = *(const float4*)&bc [tok * 32 + j4];
            *(float4*)&sC_[t][j4] = *(const float4*)&bc [tok * 32 + 16 + j4];
        }
        __syncthreads();

#pragma unroll 7
        for (int t = 0; t < TCH; ++t) {
            float dtv = sdt[t][dl];
            float uv  = su_[t][dl];
            float Bv  = sB_[t][s];
            float Cv  = sC_[t][s];
            float dA  = __expf(dtv * Ads);
            h = dA * h + (dtv * uv) * Bv;
            sprod[t][dl * 17 + s] = h * Cv;
        }
        __syncthreads();

        for (int i = tid; i < TCH * 16; i += 256) {
            int t = i >> 4, dl2 = i & 15;
            float sum = 0.f;
#pragma unroll
            for (int j = 0; j < 16; ++j) sum += sprod[t][dl2 * 17 + j];
            float uv = su_[t][dl2];
            float zv = sz_[t][dl2];
            float sig = 1.f / (1.f + __expf(-zv));
            y[(size_t)(b * LSEQ + c0 + t) * DINNER + dg * 16 + dl2] =
                __float2bfloat16((sum + uv * Dd2) * (zv * sig));
        }
        __syncthreads();
    }
}

// ---------------------------------------------------------------------------
extern "C" void kernel_launch(void* const* d_in, const int* in_sizes, int n_in,
                              void* d_out, int out_size, void* d_ws, size_t ws_size,
                              hipStream_t stream)
{
    const float* x         = (const float*)d_in[0];
    const float* pe_w      = (const float*)d_in[1];
    const float* pe_b      = (const float*)d_in[2];
    const float* norm_w    = (const float*)d_in[3];
    const float* norm_b    = (const float*)d_in[4];
    const float* in_proj_w = (const float*)d_in[5];
    const float* conv_w    = (const float*)d_in[6];
    const float* conv_b    = (const float*)d_in[7];
    const float* xproj_w   = (const float*)d_in[8];
    const float* dtproj_w  = (const float*)d_in[9];
    const float* dtproj_b  = (const float*)d_in[10];
    const float* A_log     = (const float*)d_in[11];
    const float* D_param   = (const float*)d_in[12];
    const float* outproj_w = (const float*)d_in[13];
    const float* normf_w   = (const float*)d_in[14];
    const float* normf_b   = (const float*)d_in[15];

    float* ws = (float*)d_ws;
    float* residual = ws;                       // 301056 f32
    float* xz       = residual + 301056;        // 1204224 f32
    float* ubuf     = xz + 1204224;             // 602112 f32
    float* dtbuf    = ubuf + 602112;            // 602112 f32
    float* bcbuf    = dtbuf + 602112;           // 50176 f32
    __hip_bfloat16* hn      = (__hip_bfloat16*)(ws + 2759680);  // 301056 bf16
    __hip_bfloat16* ybf     = (__hip_bfloat16*)(ws + 2910208);  // 602112 bf16
    __hip_bfloat16* patches = (__hip_bfloat16*)(ws + 3211264);  // 1204224 bf16
    short* w_in  = (short*)(ws + 3813376);      // 3538944 bf16
    short* w_out = (short*)(ws + 5582848);      // 1769472 bf16
    short* w_pe  = (short*)(ws + 6467584);      // 147456 bf16

    cvt_weights<<<5328, 256, 0, stream>>>(
        in_proj_w, outproj_w, pe_w, w_in, w_out, w_pe);

    im2col<<<(NTOK * 768 + 255) / 256, 256, 0, stream>>>(x, patches);
    gemm_ln<768><<<98, 256, 0, stream>>>(
        patches, w_pe, pe_b, residual, hn, nullptr, norm_w, norm_b, 0);

    for (int i = 0; i < DEPTH; ++i) {
        int last = (i == DEPTH - 1);
        gemm_in<192><<<dim3(25, 12), 256, 0, stream>>>(
            hn, w_in + (size_t)i * 768 * DMODEL, xz, NTOK, 768);
        conv_xproj_dt<<<NTOK, 256, 0, stream>>>(
            xz, conv_w + (size_t)i * DINNER * 4, conv_b + (size_t)i * DINNER,
            xproj_w + (size_t)i * 44 * DINNER, dtproj_w + (size_t)i * DINNER * DTRANK,
            dtproj_b + (size_t)i * DINNER, ubuf, dtbuf, bcbuf);
        scan_kernel<<<192, 256, 0, stream>>>(
            ubuf, dtbuf, bcbuf, xz, A_log + (size_t)i * DINNER * DSTATE,
            D_param + (size_t)i * DINNER, ybf);
        gemm_ln<384><<<98, 256, 0, stream>>>(
            ybf, w_out + (size_t)i * DMODEL * DINNER, nullptr, residual, hn,
            last ? (float*)d_out : nullptr,
            last ? normf_w : norm_w + (i + 1) * DMODEL,
            last ? normf_b : norm_b + (i + 1) * DMODEL,
            1);
    }
}